// Round 1
// baseline (136.438 us; speedup 1.0000x reference)
//
#include <hip/hip_runtime.h>
#include <math.h>

#define NB 16
#define NA 5
#define NH 96
#define NW 96
#define TT 50
#define HW (NH*NW)        // 9216
#define APB (NA*HW)       // 46080 cells per batch

__device__ __constant__ float c_aw[NA] = {1.3221f, 3.19275f, 5.05587f, 9.47112f, 11.2364f};
__device__ __constant__ float c_ah[NA] = {1.73145f, 4.00944f, 8.09892f, 4.84053f, 10.0071f};

__device__ __forceinline__ float sigmoidf(float x) { return 1.0f / (1.0f + __expf(-x)); }

// GT record layout (16 floats per (b,t)):
// 0:gxl 1:gxr 2:gyl 3:gyr 4:gw 5:gh 6:garea 7:valid 8:winner 9:cell
// 10:tx 11:ty 12:tw 13:th 14:tcls 15:lr
__global__ void prep_kernel(const float* __restrict__ target,
                            float* __restrict__ gt,
                            float* __restrict__ out, int out_size) {
    int b = blockIdx.x;
    int t = threadIdx.x;            // blockDim.x = 64
    __shared__ int s_cell[TT];
    __shared__ int s_valid[TT];
    if (b == 0) {
        for (int k = t; k < out_size; k += blockDim.x) out[k] = 0.0f;
    }
    if (t < TT) {
        const float* tg = target + (b*TT + t)*6;
        float tcls = tg[0];
        float gx = tg[1]*NW, gy = tg[2]*NH, gw = tg[3]*NW, gh = tg[4]*NH;
        float lr = tg[5];
        // valid = cumprod(x != 0) up to t
        int valid = 1;
        for (int u = 0; u <= t; ++u)
            if (target[(b*TT + u)*6 + 1] == 0.0f) { valid = 0; break; }
        // best anchor: argmax IoU((0,0,aw,ah),(0,0,gw,gh)); first-max wins (strict >)
        int best = 0; float bestiou = -1.0f;
        for (int a = 0; a < NA; ++a) {
            float inter = fminf(gw, c_aw[a]) * fminf(gh, c_ah[a]);
            float iou = inter / (gw*gh + c_aw[a]*c_ah[a] - inter);
            if (iou > bestiou) { bestiou = iou; best = a; }
        }
        int gi = (int)gx, gj = (int)gy;
        int cell = best*HW + gj*NW + gi;
        s_cell[t] = cell; s_valid[t] = valid;
        float* r = gt + (b*TT + t)*16;
        r[0] = gx - 0.5f*gw; r[1] = gx + 0.5f*gw;
        r[2] = gy - 0.5f*gh; r[3] = gy + 0.5f*gh;
        r[4] = gw; r[5] = gh; r[6] = gw*gh;
        r[7] = (float)valid;
        r[9] = (float)cell;
        r[10] = gx - (float)gi;  r[11] = gy - (float)gj;
        r[12] = logf(gw / c_aw[best]); r[13] = logf(gh / c_ah[best]);
        r[14] = tcls; r[15] = lr;
    }
    __syncthreads();
    if (t < TT) {
        // winner = last valid t mapping to this cell (scan scatter = last-write-wins)
        int winner = s_valid[t];
        if (winner) {
            for (int u = t + 1; u < TT; ++u)
                if (s_valid[u] && s_cell[u] == s_cell[t]) { winner = 0; break; }
        }
        gt[(b*TT + t)*16 + 8] = (float)winner;
    }
}

__global__ __launch_bounds__(256)
void loss_kernel(const float* __restrict__ outp,
                 const float* __restrict__ gt,
                 float* __restrict__ loss) {
    __shared__ float sg[TT*16];
    int b = blockIdx.y;
    int tid = threadIdx.x;
    for (int k = tid; k < TT*16; k += 256) sg[k] = gt[b*TT*16 + k];
    __syncthreads();

    int lt  = blockIdx.x*256 + tid;     // cell within batch, 0..APB
    int a   = lt / HW;
    int rem = lt - a*HW;
    int j   = rem / NW;
    int i   = rem - j*NW;

    const float* base = outp + ((b*NA + a)*8)*HW + rem;
    float o0 = base[0*HW], o1 = base[1*HW], o2 = base[2*HW], o3 = base[3*HW];
    float o4 = base[4*HW], o5 = base[5*HW], o6 = base[6*HW], o7 = base[7*HW];

    float px = sigmoidf(o0) + (float)i;
    float py = sigmoidf(o1) + (float)j;
    float pw = __expf(o2) * c_aw[a];
    float ph = __expf(o3) * c_ah[a];
    float pxl = px - 0.5f*pw, pxr = px + 0.5f*pw;
    float pyl = py - 0.5f*ph, pyr = py + 0.5f*ph;
    float parea = pw*ph;

    int assigned = -1;
    bool over = false;     // any valid gt with IoU > 0.6
    for (int t = 0; t < TT; ++t) {
        const float* r = sg + t*16;
        if (r[7] != 0.0f) {
            float uw = fmaxf(pxr, r[1]) - fminf(pxl, r[0]);
            float uh = fmaxf(pyr, r[3]) - fminf(pyl, r[2]);
            float cw = pw + r[4] - uw;
            float ch = ph + r[5] - uh;
            float carea = (cw <= 0.0f || ch <= 0.0f) ? 0.0f : cw*ch;
            // iou > 0.6  <=>  1.6*carea > 0.6*(parea+garea)   (no divide)
            over = over || (1.6f*carea > 0.6f*(parea + r[6]));
            if (r[8] != 0.0f && (int)r[9] == lt) assigned = t;
        }
    }

    float conf = sigmoidf(o4);
    float acc;
    if (assigned >= 0) {
        const float* r = sg + assigned*16;
        float uw = fmaxf(pxr, r[1]) - fminf(pxl, r[0]);
        float uh = fmaxf(pyr, r[3]) - fminf(pyl, r[2]);
        float cw = pw + r[4] - uw;
        float ch = ph + r[5] - uh;
        float carea = (cw <= 0.0f || ch <= 0.0f) ? 0.0f : cw*ch;
        float tconf = carea / (parea + r[6] - carea);
        float dc = conf - tconf;
        acc = 2.5f*dc*dc;                       // 0.5 * OBJECT_SCALE(5)
        float dx = sigmoidf(o0) - r[10];
        float dy = sigmoidf(o1) - r[11];
        float dw = o2 - r[12];
        float dh = o3 - r[13];
        acc += 0.5f*(dx*dx + dy*dy + dw*dw + dh*dh);
        // 2-class CE
        float m   = fmaxf(o5, o6);
        float lse = m + __logf(__expf(o5 - m) + __expf(o6 - m));
        float sel = (r[14] != 0.0f) ? o6 : o5;
        acc += lse - sel;
        // conf_lr: total weight = 0.5 * mse_half = 0.25
        float dl = sigmoidf(o7) - r[15];
        acc += 0.25f*dl*dl;
    } else {
        float cm = over ? 0.0f : 1.0f;          // NOOBJECT_SCALE = 1
        acc = 0.5f*cm*conf*conf;                // tconf = 0
    }

    // wave64 + block reduction
    for (int off = 32; off > 0; off >>= 1) acc += __shfl_down(acc, off, 64);
    __shared__ float ssum[4];
    int lane = tid & 63, wid = tid >> 6;
    if (lane == 0) ssum[wid] = acc;
    __syncthreads();
    if (tid == 0) {
        float s = (ssum[0] + ssum[1]) + (ssum[2] + ssum[3]);
        atomicAdd(loss, s * (1.0f/NB));
    }
}

extern "C" void kernel_launch(void* const* d_in, const int* in_sizes, int n_in,
                              void* d_out, int out_size, void* d_ws, size_t ws_size,
                              hipStream_t stream) {
    const float* output = (const float*)d_in[0];
    const float* target = (const float*)d_in[1];
    float* gtbuf = (float*)d_ws;                 // NB*TT*16 floats = 51.2 KB
    float* out   = (float*)d_out;

    hipLaunchKernelGGL(prep_kernel, dim3(NB), dim3(64), 0, stream,
                       target, gtbuf, out, out_size);
    dim3 grid(APB/256, NB);                      // 180 x 16
    hipLaunchKernelGGL(loss_kernel, grid, dim3(256), 0, stream,
                       output, gtbuf, out);
}

// Round 2
// 125.365 us; speedup vs baseline: 1.0883x; 1.0883x over previous
//
#include <hip/hip_runtime.h>
#include <math.h>

#define NB 16
#define NA 5
#define NH 96
#define NW 96
#define TT 50
#define HW (NH*NW)        // 9216
#define APB (NA*HW)       // 46080 cells per batch

__device__ __constant__ float c_aw[NA] = {1.3221f, 3.19275f, 5.05587f, 9.47112f, 11.2364f};
__device__ __constant__ float c_ah[NA] = {1.73145f, 4.00944f, 8.09892f, 4.84053f, 10.0071f};

__device__ __forceinline__ float sigmoidf(float x) { return 1.0f / (1.0f + __expf(-x)); }

// GT record layout (16 floats per (b,t)), 64B-aligned:
//  0:gxl 1:gxr 2:gyl 3:gyr 4:g06(=0.6*garea, or 1e30 if invalid)
//  5:cell (int bitcast; -1 unless winner)  6:garea 7:pad
//  8:tx 9:ty 10:tw 11:th 12:tcls 13:lr 14:pad 15:pad
__global__ void prep_kernel(const float* __restrict__ target,
                            float* __restrict__ gt,
                            float* __restrict__ out, int out_size) {
    int b = blockIdx.x;
    int t = threadIdx.x;            // blockDim.x = 64
    __shared__ int s_cell[TT];
    __shared__ int s_valid[TT];
    if (b == 0) {
        for (int k = t; k < out_size; k += 64) out[k] = 0.0f;
    }
    // valid = cumprod(x != 0): prefix property -> one ballot
    float xraw = (t < TT) ? target[(b*TT + t)*6 + 1] : 1.0f;
    unsigned long long m = __ballot(xraw != 0.0f);
    int valid = 0;
    if (t < TT) valid = (((~m) & ((2ull << t) - 1ull)) == 0ull) ? 1 : 0;

    float gx=0, gy=0, gw=1, gh=1, tcls=0, lr=0;
    int cell = -2, best = 0;
    if (t < TT) {
        const float* tg = target + (b*TT + t)*6;
        tcls = tg[0];
        gx = tg[1]*NW; gy = tg[2]*NH; gw = tg[3]*NW; gh = tg[4]*NH;
        lr = tg[5];
        float bestiou = -1.0f;
        for (int a = 0; a < NA; ++a) {
            float inter = fminf(gw, c_aw[a]) * fminf(gh, c_ah[a]);
            float iou = inter / (gw*gh + c_aw[a]*c_ah[a] - inter);
            if (iou > bestiou) { bestiou = iou; best = a; }
        }
        int gi = (int)gx, gj = (int)gy;
        cell = best*HW + gj*NW + gi;
        s_cell[t]  = valid ? cell : -2;
        s_valid[t] = valid;
    }
    __syncthreads();
    if (t < TT) {
        // winner = last valid t mapping to this cell (scan scatter = last-write-wins)
        int winner = valid;
        if (winner) {
            for (int u = t + 1; u < TT; ++u)
                if (s_valid[u] && s_cell[u] == cell) { winner = 0; break; }
        }
        float* r = gt + (b*TT + t)*16;
        if (valid) {
            r[0] = gx - 0.5f*gw; r[1] = gx + 0.5f*gw;
            r[2] = gy - 0.5f*gh; r[3] = gy + 0.5f*gh;
            r[4] = 0.6f*gw*gh;
            r[5] = __int_as_float(winner ? cell : -1);
            r[6] = gw*gh;
        } else {
            r[0] = 0.0f; r[1] = 0.0f; r[2] = 0.0f; r[3] = 0.0f;
            r[4] = 1e30f;                    // never exceeds threshold
            r[5] = __int_as_float(-1);
            r[6] = 0.0f;
        }
        r[7] = 0.0f;
        int gi = (int)gx, gj = (int)gy;
        r[8]  = gx - (float)gi;  r[9] = gy - (float)gj;
        r[10] = logf(gw / c_aw[best]); r[11] = logf(gh / c_ah[best]);
        r[12] = tcls; r[13] = lr; r[14] = 0.0f; r[15] = 0.0f;
    }
}

__global__ __launch_bounds__(256)
void loss_kernel(const float* __restrict__ outp,
                 const float* __restrict__ gt,
                 float* __restrict__ loss) {
    int b   = blockIdx.y;
    int tid = threadIdx.x;
    int lt  = blockIdx.x*256 + tid;     // cell within batch, 0..APB
    int a   = lt / HW;
    int rem = lt - a*HW;
    int j   = rem / NW;
    int i   = rem - j*NW;

    const float* base = outp + (size_t)((b*NA + a)*8)*HW + rem;
    float o0 = base[0*HW], o1 = base[1*HW], o2 = base[2*HW], o3 = base[3*HW];
    float o4 = base[4*HW], o5 = base[5*HW], o6 = base[6*HW], o7 = base[7*HW];

    float sx = sigmoidf(o0), sy = sigmoidf(o1);
    float px = sx + (float)i;
    float py = sy + (float)j;
    float pw = __expf(o2) * c_aw[a];
    float ph = __expf(o3) * c_ah[a];
    float pxl = px - 0.5f*pw, pxr = px + 0.5f*pw;
    float pyl = py - 0.5f*ph, pyr = py + 0.5f*ph;
    float parea = pw*ph;
    float p6 = 0.6f*parea;

    // block-uniform GT base -> scalar (SMEM) loads inside the loop
    const float* g = gt + b*(TT*16);

    int assigned = -1;
    bool over = false;
    #pragma unroll 5
    for (int t = 0; t < TT; ++t) {
        const float* r = g + t*16;
        float gxl = r[0], gxr = r[1], gyl = r[2], gyr = r[3];
        float g06 = r[4];
        int   ct  = __float_as_int(r[5]);
        float cw = fminf(pxr, gxr) - fmaxf(pxl, gxl);
        float ch = fminf(pyr, gyr) - fmaxf(pyl, gyl);
        float carea = fmaxf(cw, 0.0f) * fmaxf(ch, 0.0f);
        over = over || (1.6f*carea > p6 + g06);
        if (ct == lt) assigned = t;
    }

    float conf = sigmoidf(o4);
    float acc;
    if (assigned >= 0) {
        const float4* r4 = (const float4*)(g + assigned*16);
        float4 ra = r4[0];   // gxl gxr gyl gyr
        float4 rb = r4[1];   // g06 cell garea pad
        float4 rc = r4[2];   // tx ty tw th
        float4 rd = r4[3];   // tcls lr pad pad
        float cw = fminf(pxr, ra.y) - fmaxf(pxl, ra.x);
        float ch = fminf(pyr, ra.w) - fmaxf(pyl, ra.z);
        float carea = fmaxf(cw, 0.0f) * fmaxf(ch, 0.0f);
        float tconf = carea / (parea + rb.z - carea);
        float dc = conf - tconf;
        acc = 2.5f*dc*dc;                       // 0.5 * OBJECT_SCALE(5)
        float dx = sx - rc.x;
        float dy = sy - rc.y;
        float dw = o2 - rc.z;
        float dh = o3 - rc.w;
        acc += 0.5f*(dx*dx + dy*dy + dw*dw + dh*dh);
        // 2-class CE
        float mm  = fmaxf(o5, o6);
        float lse = mm + __logf(__expf(o5 - mm) + __expf(o6 - mm));
        float sel = (rd.x != 0.0f) ? o6 : o5;
        acc += lse - sel;
        // conf_lr: 0.5 * mse_half = 0.25
        float dl = sigmoidf(o7) - rd.y;
        acc += 0.25f*dl*dl;
    } else {
        acc = over ? 0.0f : 0.5f*conf*conf;     // NOOBJECT_SCALE=1, tconf=0
    }

    // wave64 + block reduction
    for (int off = 32; off > 0; off >>= 1) acc += __shfl_down(acc, off, 64);
    __shared__ float ssum[4];
    int lane = tid & 63, wid = tid >> 6;
    if (lane == 0) ssum[wid] = acc;
    __syncthreads();
    if (tid == 0) {
        float s = (ssum[0] + ssum[1]) + (ssum[2] + ssum[3]);
        atomicAdd(loss, s * (1.0f/NB));
    }
}

extern "C" void kernel_launch(void* const* d_in, const int* in_sizes, int n_in,
                              void* d_out, int out_size, void* d_ws, size_t ws_size,
                              hipStream_t stream) {
    const float* output = (const float*)d_in[0];
    const float* target = (const float*)d_in[1];
    float* gtbuf = (float*)d_ws;                 // NB*TT*16 floats = 51.2 KB
    float* out   = (float*)d_out;

    hipLaunchKernelGGL(prep_kernel, dim3(NB), dim3(64), 0, stream,
                       target, gtbuf, out, out_size);
    dim3 grid(APB/256, NB);                      // 180 x 16
    hipLaunchKernelGGL(loss_kernel, grid, dim3(256), 0, stream,
                       output, gtbuf, out);
}

// Round 3
// 97.878 us; speedup vs baseline: 1.3940x; 1.2808x over previous
//
#include <hip/hip_runtime.h>
#include <math.h>

#define NB 16
#define NA 5
#define NH 96
#define NW 96
#define TT 50
#define HW (NH*NW)        // 9216
#define APB (NA*HW)       // 46080 cells per batch
#define CPT 4             // cells per thread in loss_kernel

__device__ __constant__ float c_aw[NA] = {1.3221f, 3.19275f, 5.05587f, 9.47112f, 11.2364f};
__device__ __constant__ float c_ah[NA] = {1.73145f, 4.00944f, 8.09892f, 4.84053f, 10.0071f};

__device__ __forceinline__ float sigmoidf(float x) { return 1.0f / (1.0f + __expf(-x)); }

// GT record: 8 floats per (b,t): [gxl, gxr, gyl, gyr, g06n(=-0.6*garea or -1e30), pad,pad,pad]
// prep also computes the FULL assigned-cell loss for each winner and pre-subtracts the
// noobj term loss_kernel will add for that cell, so loss_kernel is branch-free per cell.
__global__ void prep_kernel(const float* __restrict__ target,
                            const float* __restrict__ outp,
                            float* __restrict__ gt,
                            float* __restrict__ out) {
    int b = blockIdx.x;
    int t = threadIdx.x;            // blockDim.x = 64 (one wave)
    __shared__ float s_gxl[TT], s_gxr[TT], s_gyl[TT], s_gyr[TT], s_g06n[TT];
    __shared__ int   s_cell[TT], s_valid[TT];

    float xraw = (t < TT) ? target[(b*TT + t)*6 + 1] : 1.0f;
    unsigned long long m = __ballot(xraw != 0.0f);

    int valid = 0, best = 0, cell = -1, gi = 0, gj = 0;
    float gx=0, gy=0, gw=1, gh=1, tcls=0, lr=0;
    float gxl=0, gxr=0, gyl=0, gyr=0, g06n=-1e30f;
    if (t < TT) {
        valid = (((~m) & ((2ull << t) - 1ull)) == 0ull) ? 1 : 0;
        const float* tg = target + (b*TT + t)*6;
        tcls = tg[0];
        gx = tg[1]*NW; gy = tg[2]*NH; gw = tg[3]*NW; gh = tg[4]*NH;
        lr = tg[5];
        float bestiou = -1.0f;
        for (int a = 0; a < NA; ++a) {
            float inter = fminf(gw, c_aw[a]) * fminf(gh, c_ah[a]);
            float iou = inter / (gw*gh + c_aw[a]*c_ah[a] - inter);
            if (iou > bestiou) { bestiou = iou; best = a; }
        }
        gi = (int)gx; gj = (int)gy;
        cell = best*HW + gj*NW + gi;
        if (valid) {
            gxl = gx - 0.5f*gw; gxr = gx + 0.5f*gw;
            gyl = gy - 0.5f*gh; gyr = gy + 0.5f*gh;
            g06n = -0.6f*gw*gh;
        }
        s_gxl[t] = gxl; s_gxr[t] = gxr; s_gyl[t] = gyl; s_gyr[t] = gyr;
        s_g06n[t] = g06n;
        s_cell[t] = valid ? cell : -1;
        s_valid[t] = valid;
        float* r = gt + (b*TT + t)*8;
        r[0] = gxl; r[1] = gxr; r[2] = gyl; r[3] = gyr; r[4] = g06n;
        r[5] = 0.0f; r[6] = 0.0f; r[7] = 0.0f;
    }
    __syncthreads();

    float acc = 0.0f;
    if (t < TT && valid) {
        int winner = 1;   // last valid t mapping to this cell wins (scan = last-write-wins)
        for (int u = t + 1; u < TT; ++u)
            if (s_valid[u] && s_cell[u] == cell) { winner = 0; break; }
        if (winner) {
            int a = cell / HW;
            int rem = cell - a*HW;
            const float* base = outp + (size_t)((b*NA + a)*8)*HW + rem;
            float o0 = base[0*HW], o1 = base[1*HW], o2 = base[2*HW], o3 = base[3*HW];
            float o4 = base[4*HW], o5 = base[5*HW], o6 = base[6*HW], o7 = base[7*HW];
            float sx = sigmoidf(o0), sy = sigmoidf(o1);
            float px = sx + (float)gi, py = sy + (float)gj;
            float pw = __expf(o2) * c_aw[a];
            float ph = __expf(o3) * c_ah[a];
            float pxl = px - 0.5f*pw, pxr = px + 0.5f*pw;
            float pyl = py - 0.5f*ph, pyr = py + 0.5f*ph;
            float parea = pw*ph, p6 = 0.6f*parea;
            // replicate loss_kernel's noobj computation exactly
            float maxv = -1e30f;
            for (int u = 0; u < TT; ++u) {
                float cw = fminf(pxr, s_gxr[u]) - fmaxf(pxl, s_gxl[u]);
                float ch = fminf(pyr, s_gyr[u]) - fmaxf(pyl, s_gyl[u]);
                float carea = fmaxf(cw, 0.0f) * fmaxf(ch, 0.0f);
                maxv = fmaxf(maxv, fmaf(1.6f, carea, s_g06n[u]));
            }
            float conf = sigmoidf(o4);
            float noobj = (maxv > p6) ? 0.0f : 0.5f*conf*conf;
            // assigned-cell loss
            float cw = fminf(pxr, gxr) - fmaxf(pxl, gxl);
            float ch = fminf(pyr, gyr) - fmaxf(pyl, gyl);
            float carea = fmaxf(cw, 0.0f) * fmaxf(ch, 0.0f);
            float tconf = carea / (parea + gw*gh - carea);
            float dc = conf - tconf;
            acc = 2.5f*dc*dc;                         // 0.5 * OBJECT_SCALE
            float tx = gx - (float)gi, ty = gy - (float)gj;
            float tw = logf(gw / c_aw[best]), th = logf(gh / c_ah[best]);
            float dx = sx - tx, dy = sy - ty, dw = o2 - tw, dh = o3 - th;
            acc += 0.5f*(dx*dx + dy*dy + dw*dw + dh*dh);
            float mm  = fmaxf(o5, o6);
            float lse = mm + __logf(__expf(o5 - mm) + __expf(o6 - mm));
            acc += lse - ((tcls != 0.0f) ? o6 : o5);  // 2-class CE
            float dl = sigmoidf(o7) - lr;
            acc += 0.25f*dl*dl;                       // 0.5 * mse_half(conf_lr)
            acc -= noobj;                             // loss_kernel will add it back
        }
    }
    // one wave -> shuffle reduce, single atomic per block
    for (int off = 32; off > 0; off >>= 1) acc += __shfl_down(acc, off, 64);
    if (t == 0) atomicAdd(out, acc * (1.0f/NB));
}

__global__ __launch_bounds__(256)
void loss_kernel(const float* __restrict__ outp,
                 const float* __restrict__ gt,
                 float* __restrict__ loss) {
    int b   = blockIdx.y;
    int tid = threadIdx.x;
    int q     = blockIdx.x*256 + tid;      // 0 .. APB/CPT-1
    int cell0 = q*CPT;
    int a   = cell0 / HW;                  // block-uniform: 9216 % 1024 == 0
    int rem = cell0 - a*HW;
    int j   = rem / NW;
    int i0  = rem - j*NW;

    const float* base = outp + (size_t)((b*NA + a)*8)*HW + rem;
    float4 v0 = *(const float4*)(base + 0*HW);
    float4 v1 = *(const float4*)(base + 1*HW);
    float4 v2 = *(const float4*)(base + 2*HW);
    float4 v3 = *(const float4*)(base + 3*HW);
    float4 v4 = *(const float4*)(base + 4*HW);
    float o0[CPT] = {v0.x, v0.y, v0.z, v0.w};
    float o1[CPT] = {v1.x, v1.y, v1.z, v1.w};
    float o2[CPT] = {v2.x, v2.y, v2.z, v2.w};
    float o3[CPT] = {v3.x, v3.y, v3.z, v3.w};
    float o4[CPT] = {v4.x, v4.y, v4.z, v4.w};

    float aw = c_aw[a], ah = c_ah[a];
    float pxl[CPT], pxr[CPT], pyl[CPT], pyr[CPT], p6[CPT], maxv[CPT];
    #pragma unroll
    for (int c = 0; c < CPT; ++c) {
        float sx = sigmoidf(o0[c]), sy = sigmoidf(o1[c]);
        float px = sx + (float)(i0 + c);
        float py = sy + (float)j;
        float pw = __expf(o2[c]) * aw;
        float ph = __expf(o3[c]) * ah;
        pxl[c] = px - 0.5f*pw; pxr[c] = px + 0.5f*pw;
        pyl[c] = py - 0.5f*ph; pyr[c] = py + 0.5f*ph;
        p6[c]  = 0.6f*(pw*ph);
        maxv[c] = -1e30f;
    }

    const float* g = gt + b*(TT*8);        // block-uniform -> scalar loads
    #pragma unroll 2
    for (int t = 0; t < TT; ++t) {
        const float* r = g + t*8;
        float gxl = r[0], gxr = r[1], gyl = r[2], gyr = r[3], g06n = r[4];
        #pragma unroll
        for (int c = 0; c < CPT; ++c) {
            float cw = fminf(pxr[c], gxr) - fmaxf(pxl[c], gxl);
            float ch = fminf(pyr[c], gyr) - fmaxf(pyl[c], gyl);
            float carea = fmaxf(cw, 0.0f) * fmaxf(ch, 0.0f);
            maxv[c] = fmaxf(maxv[c], fmaf(1.6f, carea, g06n));
        }
    }

    float acc = 0.0f;
    #pragma unroll
    for (int c = 0; c < CPT; ++c) {
        float conf = sigmoidf(o4[c]);
        acc += (maxv[c] > p6[c]) ? 0.0f : 0.5f*conf*conf;
    }

    // wave64 + block reduction
    for (int off = 32; off > 0; off >>= 1) acc += __shfl_down(acc, off, 64);
    __shared__ float ssum[4];
    int lane = tid & 63, wid = tid >> 6;
    if (lane == 0) ssum[wid] = acc;
    __syncthreads();
    if (tid == 0) {
        float s = (ssum[0] + ssum[1]) + (ssum[2] + ssum[3]);
        atomicAdd(loss, s * (1.0f/NB));
    }
}

extern "C" void kernel_launch(void* const* d_in, const int* in_sizes, int n_in,
                              void* d_out, int out_size, void* d_ws, size_t ws_size,
                              hipStream_t stream) {
    const float* output = (const float*)d_in[0];
    const float* target = (const float*)d_in[1];
    float* gtbuf = (float*)d_ws;                 // NB*TT*8 floats = 25.6 KB
    float* out   = (float*)d_out;

    hipMemsetAsync(out, 0, (size_t)out_size*sizeof(float), stream);
    hipLaunchKernelGGL(prep_kernel, dim3(NB), dim3(64), 0, stream,
                       target, output, gtbuf, out);
    dim3 grid(APB/(256*CPT), NB);                // 45 x 16 = 720 blocks
    hipLaunchKernelGGL(loss_kernel, grid, dim3(256), 0, stream,
                       output, gtbuf, out);
}